// Round 15
// baseline (261.365 us; speedup 1.0000x reference)
//
#include <hip/hip_runtime.h>

typedef unsigned short u16;
typedef unsigned int u32;
typedef unsigned long long u64;

#define BB 8
#define LL 2048
#define DD 256
#define NB (BB * LL)      // 16384 rows per branch
#define NBR 4
#define NRT (NBR * NB)    // 65536 batched rows
#define NCH 64
#define CHL (LL / NCH)    // 32
#define CAP 64

typedef __attribute__((ext_vector_type(8))) __bf16 bf16x8;
typedef __attribute__((ext_vector_type(4))) float f32x4;

__device__ __forceinline__ float b2f(u16 u) {
    union { u32 u; float f; } x; x.u = ((u32)u) << 16; return x.f;
}
__device__ __forceinline__ u16 f2b(float f) {
    union { float f; u32 u; } x; x.f = f;
    u32 r = (x.u >> 16) & 1u;
    x.u += 0x7FFFu + r;
    return (u16)(x.u >> 16);
}
__device__ __forceinline__ float sigm(float x) { return 1.f / (1.f + __expf(-x)); }

#define GLD(gp, lp) __builtin_amdgcn_global_load_lds( \
    (const __attribute__((address_space(1))) void*)(gp), \
    (__attribute__((address_space(3))) void*)(lp), 16, 0, 0)

// ---- prologue über-kernel ---------------------------------------------------
// Block order: [0,256) Wc1T | [256,256+NB) CSR | transposes ×7 | Xb cast.
struct PrologArgs {
    const float* s[7];
    u16* d[7];
    int K[7], N[7];
    int begT[8];
    int xbBeg, xbEnd;
    const float* xsrc;
    const int* maskp;
    u16* xdst;
    const float* Adj;
    const int* ri0; const int* ri1; const int* ri2;
    int* csr4; int* cnt; float* deg;
    const float* wout1; const float* we1;
    u16* wc1t;
};
__global__ void prolog_kernel(PrologArgs a) {
    int blk = blockIdx.x;
    if (blk < 256) {                               // Wc1T[j][i] = sum_k Wout1[i][k]*We1[k][j]
        int ii = blk;
        int j = threadIdx.x;
        const float* wrow = a.wout1 + (size_t)ii * 256;
        const float* wcol = a.we1 + j;
        float a0 = 0.f, a1 = 0.f, a2 = 0.f, a3 = 0.f;
#pragma unroll 4
        for (int k = 0; k < 256; k += 4) {
            a0 += wrow[k]     * wcol[(size_t)k * 256];
            a1 += wrow[k + 1] * wcol[(size_t)(k + 1) * 256];
            a2 += wrow[k + 2] * wcol[(size_t)(k + 2) * 256];
            a3 += wrow[k + 3] * wcol[(size_t)(k + 3) * 256];
        }
        a.wc1t[(size_t)j * 256 + ii] = f2b((a0 + a1) + (a2 + a3));
        return;
    }
    if (blk < 256 + NB) {                          // CSR: 1 row/block, 4-wave compaction
        __shared__ int lidx[4][CAP];
        __shared__ int lcnt[4], pre[4], tot;
        int row = blk - 256;
        int w = threadIdx.x >> 6, lane = threadIdx.x & 63;
        int rowb = row & ~(LL - 1);                // (b<<11)
        const float* aseg = a.Adj + (size_t)row * LL + w * 512;
        float4 v0 = *(const float4*)(aseg + lane * 4);
        float4 v1 = *(const float4*)(aseg + 256 + lane * 4);
        int base = 0;
#pragma unroll
        for (int it = 0; it < 2; ++it) {
            float4 v = it ? v1 : v0;
#pragma unroll
            for (int e = 0; e < 4; ++e) {
                float f = (e == 0) ? v.x : (e == 1) ? v.y : (e == 2) ? v.z : v.w;
                bool nz = (f != 0.f);
                u64 m = __ballot(nz);
                if (nz) {
                    int pos = base + __popcll(m & ((1ull << lane) - 1ull));
                    if (pos < CAP) lidx[w][pos] = w * 512 + it * 256 + lane * 4 + e;
                }
                base += __popcll(m);
            }
        }
        if (lane == 0) lcnt[w] = base;
        __syncthreads();
        if (threadIdx.x == 0) {
            int s = 0;
#pragma unroll
            for (int k = 0; k < 4; ++k) { pre[k] = s; s += lcnt[k]; }
            tot = s;
        }
        __syncthreads();
        int cw = lcnt[w]; if (cw > CAP) cw = CAP;
        int pw = pre[w];
        for (int k = lane; k < cw; k += 64) {
            int gpos = pw + k;
            if (gpos < CAP) {
                int j = lidx[w][k];
                a.csr4[((size_t)(3 * NB + row)) * CAP + gpos] = j;
                a.csr4[((size_t)(0 * NB + row)) * CAP + gpos] = a.ri0[rowb + j];
                a.csr4[((size_t)(1 * NB + row)) * CAP + gpos] = a.ri1[rowb + j];
                a.csr4[((size_t)(2 * NB + row)) * CAP + gpos] = a.ri2[rowb + j];
            }
        }
        if (threadIdx.x == 0) {
            int t = tot;
            a.cnt[row] = t < CAP ? t : CAP;
            a.deg[row] = (float)(t < 1 ? 1 : t);
        }
        return;
    }
    if (blk >= a.xbBeg) {                          // Xb = mask(X) -> bf16
        int g = (blk - a.xbBeg) * 256 + threadIdx.x;
        int r = g >> 6;
        float4 v = a.maskp[r] ? *(const float4*)(a.xsrc + (size_t)g * 4)
                              : (float4){0.f, 0.f, 0.f, 0.f};
        union { u64 q; u16 h[4]; } pk;
        pk.h[0] = f2b(v.x); pk.h[1] = f2b(v.y); pk.h[2] = f2b(v.z); pk.h[3] = f2b(v.w);
        *(u64*)(a.xdst + (size_t)g * 4) = pk.q;
        return;
    }
    int i = 0;                                     // weight transposes
    while (blk >= a.begT[i + 1]) ++i;
    int idx = (blk - a.begT[i]) * 256 + threadIdx.x;
    int K = a.K[i], N = a.N[i];
    if (idx >= K * N) return;
    int k = idx / N, n = idx - k * N;
    a.d[i][(size_t)n * K + k] = f2b(a.s[i][idx]);
}

// ------- Win GEMM: 128x256 tile; Z = [Xb@Win1 ; Xb@Win2], planar z/g --------
__global__ __launch_bounds__(256)
void gemm_win_kernel(const u16* __restrict__ Xb,
                     const u16* __restrict__ Bt1, const u16* __restrict__ Bt2,
                     u16* __restrict__ Zz, u16* __restrict__ Zg)
{
    __shared__ __align__(16) u16 As[2][128 * 32];
    __shared__ __align__(16) u16 Bs[2][256 * 32];
    int tid = threadIdx.x, lane = tid & 63;
    int w = tid >> 6, wm = w >> 1, wn = w & 1;
    int rowBase = blockIdx.x * 128, colBase = blockIdx.y * 256;
    const u16* Bt = (rowBase < NB) ? Bt1 : Bt2;
    int arow = rowBase & (NB - 1);

    const u16* pa[2];
    const u16* pb[4];
#pragma unroll
    for (int rep = 0; rep < 2; ++rep) {
        int s = rep * 256 + tid;
        pa[rep] = Xb + (size_t)(arow + (s >> 2)) * 256 + ((s & 3) << 3);
    }
#pragma unroll
    for (int rep = 0; rep < 4; ++rep) {
        int s = rep * 256 + tid;
        pb[rep] = Bt + (size_t)(colBase + (s >> 2)) * 256 + ((s & 3) << 3);
    }

    f32x4 acc[4][8];
#pragma unroll
    for (int m = 0; m < 4; ++m)
#pragma unroll
        for (int n = 0; n < 8; ++n) acc[m][n] = (f32x4){0.f, 0.f, 0.f, 0.f};

#pragma unroll
    for (int rep = 0; rep < 2; ++rep) GLD(pa[rep], As[0] + (rep * 256 + tid) * 8);
#pragma unroll
    for (int rep = 0; rep < 4; ++rep) GLD(pb[rep], Bs[0] + (rep * 256 + tid) * 8);
    int p = 0;
    for (int t = 0; t < 8; ++t) {
        if (t + 1 < 8) {
            int k0 = (t + 1) * 32;
#pragma unroll
            for (int rep = 0; rep < 2; ++rep) GLD(pa[rep] + k0, As[p ^ 1] + (rep * 256 + tid) * 8);
#pragma unroll
            for (int rep = 0; rep < 4; ++rep) GLD(pb[rep] + k0, Bs[p ^ 1] + (rep * 256 + tid) * 8);
            asm volatile("s_waitcnt vmcnt(6)" ::: "memory");
        } else {
            asm volatile("s_waitcnt vmcnt(0)" ::: "memory");
        }
        __builtin_amdgcn_s_barrier();
        int kq = (lane >> 4) << 3;
        bf16x8 av[4], bw[8];
#pragma unroll
        for (int m = 0; m < 4; ++m)
            av[m] = *(const bf16x8*)(As[p] + (wm * 64 + m * 16 + (lane & 15)) * 32 + kq);
#pragma unroll
        for (int n = 0; n < 8; ++n)
            bw[n] = *(const bf16x8*)(Bs[p] + (wn * 128 + n * 16 + (lane & 15)) * 32 + kq);
#pragma unroll
        for (int m = 0; m < 4; ++m)
#pragma unroll
            for (int n = 0; n < 8; ++n)
                acc[m][n] = __builtin_amdgcn_mfma_f32_16x16x32_bf16(av[m], bw[n], acc[m][n], 0, 0, 0);
        __builtin_amdgcn_s_barrier();
        p ^= 1;
    }

    u16* Cz = (colBase < 256) ? Zz : Zg;
    int cBase = wn * 128 + (lane & 15);
    int rBase = rowBase + wm * 64 + ((lane >> 4) << 2);
#pragma unroll
    for (int m = 0; m < 4; ++m)
#pragma unroll
        for (int n = 0; n < 8; ++n)
#pragma unroll
            for (int r = 0; r < 4; ++r)
                Cz[(size_t)(rBase + m * 16 + r) * 256 + (cBase + n * 16)] = f2b(acc[m][n][r]);
}

// --------- generic GEMM: 128x256 tile, 2-way A split, 3-way B weights -------
// mode 1: bias(f32)+relu+bf16; mode 2: plain bf16
__global__ __launch_bounds__(256)
void gemm_kernel(const u16* __restrict__ A1, const u16* __restrict__ A2, int asplit,
                 const u16* __restrict__ Bt1, const u16* __restrict__ Bt2,
                 const u16* __restrict__ Bt3, int split1, int split2,
                 void* __restrict__ Cout, const float* __restrict__ bias,
                 int N, int K, int mode)
{
    __shared__ __align__(16) u16 As[2][128 * 32];
    __shared__ __align__(16) u16 Bs[2][256 * 32];
    int tid = threadIdx.x;
    int lane = tid & 63;
    int w = tid >> 6, wm = w >> 1, wn = w & 1;
    int rowBase = blockIdx.x * 128, colBase = blockIdx.y * 256;
    const u16* Bt = (rowBase < split1) ? Bt1 : (rowBase < split2) ? Bt2 : Bt3;
    const u16* Arow = (rowBase < asplit) ? A1 + (size_t)rowBase * K
                                         : A2 + (size_t)(rowBase - asplit) * K;

    const u16* pa[2];
    const u16* pb[4];
#pragma unroll
    for (int rep = 0; rep < 2; ++rep) {
        int s = rep * 256 + tid;
        pa[rep] = Arow + (size_t)(s >> 2) * K + ((s & 3) << 3);
    }
#pragma unroll
    for (int rep = 0; rep < 4; ++rep) {
        int s = rep * 256 + tid;
        pb[rep] = Bt + (size_t)(colBase + (s >> 2)) * K + ((s & 3) << 3);
    }

    f32x4 acc[4][8];
#pragma unroll
    for (int m = 0; m < 4; ++m)
#pragma unroll
        for (int n = 0; n < 8; ++n) acc[m][n] = (f32x4){0.f, 0.f, 0.f, 0.f};

    int nt = K >> 5;
#pragma unroll
    for (int rep = 0; rep < 2; ++rep) GLD(pa[rep], As[0] + (rep * 256 + tid) * 8);
#pragma unroll
    for (int rep = 0; rep < 4; ++rep) GLD(pb[rep], Bs[0] + (rep * 256 + tid) * 8);
    int p = 0;
    for (int t = 0; t < nt; ++t) {
        if (t + 1 < nt) {
            int k0 = (t + 1) << 5;
#pragma unroll
            for (int rep = 0; rep < 2; ++rep) GLD(pa[rep] + k0, As[p ^ 1] + (rep * 256 + tid) * 8);
#pragma unroll
            for (int rep = 0; rep < 4; ++rep) GLD(pb[rep] + k0, Bs[p ^ 1] + (rep * 256 + tid) * 8);
            asm volatile("s_waitcnt vmcnt(6)" ::: "memory");
        } else {
            asm volatile("s_waitcnt vmcnt(0)" ::: "memory");
        }
        __builtin_amdgcn_s_barrier();
        int kq = (lane >> 4) << 3;
        bf16x8 av[4], bw[8];
#pragma unroll
        for (int m = 0; m < 4; ++m)
            av[m] = *(const bf16x8*)(As[p] + (wm * 64 + m * 16 + (lane & 15)) * 32 + kq);
#pragma unroll
        for (int n = 0; n < 8; ++n)
            bw[n] = *(const bf16x8*)(Bs[p] + (wn * 128 + n * 16 + (lane & 15)) * 32 + kq);
#pragma unroll
        for (int m = 0; m < 4; ++m)
#pragma unroll
            for (int n = 0; n < 8; ++n)
                acc[m][n] = __builtin_amdgcn_mfma_f32_16x16x32_bf16(av[m], bw[n], acc[m][n], 0, 0, 0);
        __builtin_amdgcn_s_barrier();
        p ^= 1;
    }

    int cBase = colBase + wn * 128 + (lane & 15);
    int rBase = rowBase + wm * 64 + ((lane >> 4) << 2);
    u16* C = (u16*)Cout;
    float bz[8];
#pragma unroll
    for (int n = 0; n < 8; ++n) bz[n] = bias ? bias[cBase + n * 16] : 0.f;
#pragma unroll
    for (int m = 0; m < 4; ++m)
#pragma unroll
        for (int n = 0; n < 8; ++n)
#pragma unroll
            for (int r = 0; r < 4; ++r) {
                float v = acc[m][n][r] + bz[n];
                if (mode == 1) v = v > 0.f ? v : 0.f;
                C[(size_t)(rBase + m * 16 + r) * N + (cBase + n * 16)] = f2b(v);
            }
}

// --------- split-K2 GEMM, 128x256 tile, K=1024: z picks K-half + output -----
__global__ __launch_bounds__(256)
void gemm_splitk2_kernel(const u16* __restrict__ A, const u16* __restrict__ Bt,
                         u16* __restrict__ C0, u16* __restrict__ C1)
{
    __shared__ __align__(16) u16 As[2][128 * 32];
    __shared__ __align__(16) u16 Bs[2][256 * 32];
    int tid = threadIdx.x;
    int lane = tid & 63;
    int w = tid >> 6, wm = w >> 1, wn = w & 1;
    int rowBase = blockIdx.x * 128;
    int koff = blockIdx.z * 512;

    const u16* pa[2];
    const u16* pb[4];
#pragma unroll
    for (int rep = 0; rep < 2; ++rep) {
        int s = rep * 256 + tid;
        pa[rep] = A + (size_t)(rowBase + (s >> 2)) * 1024 + koff + ((s & 3) << 3);
    }
#pragma unroll
    for (int rep = 0; rep < 4; ++rep) {
        int s = rep * 256 + tid;
        pb[rep] = Bt + (size_t)(s >> 2) * 1024 + koff + ((s & 3) << 3);
    }

    f32x4 acc[4][8];
#pragma unroll
    for (int m = 0; m < 4; ++m)
#pragma unroll
        for (int n = 0; n < 8; ++n) acc[m][n] = (f32x4){0.f, 0.f, 0.f, 0.f};

#pragma unroll
    for (int rep = 0; rep < 2; ++rep) GLD(pa[rep], As[0] + (rep * 256 + tid) * 8);
#pragma unroll
    for (int rep = 0; rep < 4; ++rep) GLD(pb[rep], Bs[0] + (rep * 256 + tid) * 8);
    int p = 0;
    for (int t = 0; t < 16; ++t) {
        if (t + 1 < 16) {
            int k0 = (t + 1) << 5;
#pragma unroll
            for (int rep = 0; rep < 2; ++rep) GLD(pa[rep] + k0, As[p ^ 1] + (rep * 256 + tid) * 8);
#pragma unroll
            for (int rep = 0; rep < 4; ++rep) GLD(pb[rep] + k0, Bs[p ^ 1] + (rep * 256 + tid) * 8);
            asm volatile("s_waitcnt vmcnt(6)" ::: "memory");
        } else {
            asm volatile("s_waitcnt vmcnt(0)" ::: "memory");
        }
        __builtin_amdgcn_s_barrier();
        int kq = (lane >> 4) << 3;
        bf16x8 av[4], bw[8];
#pragma unroll
        for (int m = 0; m < 4; ++m)
            av[m] = *(const bf16x8*)(As[p] + (wm * 64 + m * 16 + (lane & 15)) * 32 + kq);
#pragma unroll
        for (int n = 0; n < 8; ++n)
            bw[n] = *(const bf16x8*)(Bs[p] + (wn * 128 + n * 16 + (lane & 15)) * 32 + kq);
#pragma unroll
        for (int m = 0; m < 4; ++m)
#pragma unroll
            for (int n = 0; n < 8; ++n)
                acc[m][n] = __builtin_amdgcn_mfma_f32_16x16x32_bf16(av[m], bw[n], acc[m][n], 0, 0, 0);
        __builtin_amdgcn_s_barrier();
        p ^= 1;
    }

    u16* C = blockIdx.z ? C1 : C0;
    int cBase = wn * 128 + (lane & 15);
    int rBase = rowBase + wm * 64 + ((lane >> 4) << 2);
#pragma unroll
    for (int m = 0; m < 4; ++m)
#pragma unroll
        for (int n = 0; n < 8; ++n)
#pragma unroll
            for (int r = 0; r < 4; ++r)
                C[(size_t)(rBase + m * 16 + r) * 256 + (cBase + n * 16)] = f2b(acc[m][n][r]);
}

// ------- scan with fused row-gather (si-permuted reads of shared Z) ---------
__global__ void scan_carry_kernel(const u16* __restrict__ Zz,
                                  const int* __restrict__ si0, const int* __restrict__ si1,
                                  const int* __restrict__ si2,
                                  const float* __restrict__ alog1, const float* __restrict__ alog2,
                                  float* __restrict__ carry) {
    int bid = blockIdx.x;                          // (br,b,c): 4*8*64 = 2048
    int br = bid >> 9, b = (bid >> 6) & 7, c = bid & 63;
    int d0 = threadIdx.x * 2;                      // 128 threads
    const float* al = (br < 3) ? alog1 : alog2;
    const int* sip = (br == 0) ? si0 : (br == 1) ? si1 : (br == 2) ? si2 : nullptr;
    float aA = sigm(al[d0]), aB = sigm(al[d0 + 1]);
    float hA = 0.f, hB = 0.f;
    const u16* zb = Zz + (((size_t)(br < 3 ? 0 : NB) + ((size_t)b << 11)) * DD) + d0;
    int tbase = b * LL + c * CHL;
    for (int t0 = 0; t0 < CHL; t0 += 4) {
        int r0, r1, r2, r3;
        if (sip) {
            int4 il = *(const int4*)(sip + tbase + t0);
            r0 = il.x; r1 = il.y; r2 = il.z; r3 = il.w;
        } else {
            int l0 = c * CHL + t0;
            r0 = l0; r1 = l0 + 1; r2 = l0 + 2; r3 = l0 + 3;
        }
        u32 v0 = *(const u32*)(zb + (size_t)r0 * DD);
        u32 v1 = *(const u32*)(zb + (size_t)r1 * DD);
        u32 v2 = *(const u32*)(zb + (size_t)r2 * DD);
        u32 v3 = *(const u32*)(zb + (size_t)r3 * DD);
        hA = aA * hA + (1.f - aA) * b2f((u16)v0); hB = aB * hB + (1.f - aB) * b2f((u16)(v0 >> 16));
        hA = aA * hA + (1.f - aA) * b2f((u16)v1); hB = aB * hB + (1.f - aB) * b2f((u16)(v1 >> 16));
        hA = aA * hA + (1.f - aA) * b2f((u16)v2); hB = aB * hB + (1.f - aB) * b2f((u16)(v2 >> 16));
        hA = aA * hA + (1.f - aA) * b2f((u16)v3); hB = aB * hB + (1.f - aB) * b2f((u16)(v3 >> 16));
    }
    carry[(size_t)bid * DD + d0] = hA;
    carry[(size_t)bid * DD + d0 + 1] = hB;
}

__global__ void scan_apply_kernel(const u16* __restrict__ Zz, const u16* __restrict__ Zg,
                                  const int* __restrict__ si0, const int* __restrict__ si1,
                                  const int* __restrict__ si2,
                                  const float* __restrict__ alog1, const float* __restrict__ alog2,
                                  const float* __restrict__ carry, u16* __restrict__ U4) {
    int bid = blockIdx.x;
    int br = bid >> 9, b = (bid >> 6) & 7, c = bid & 63;
    int d0 = threadIdx.x * 2;
    const float* al = (br < 3) ? alog1 : alog2;
    const int* sip = (br == 0) ? si0 : (br == 1) ? si1 : (br == 2) ? si2 : nullptr;
    float aA = sigm(al[d0]), aB = sigm(al[d0 + 1]);
    float aPA = aA, aPB = aB;
#pragma unroll
    for (int i = 0; i < 5; ++i) { aPA *= aPA; aPB *= aPB; }   // a^32
    float hA = 0.f, hB = 0.f;
    const float* cp = carry + ((size_t)((br * 8 + b) * NCH)) * DD + d0;
    for (int cc = 0; cc < c; ++cc) {
        float2 cv = *(const float2*)(cp + (size_t)cc * DD);
        hA = cv.x + aPA * hA;
        hB = cv.y + aPB * hB;
    }
    size_t base = ((size_t)(br < 3 ? 0 : NB) + ((size_t)b << 11)) * DD + d0;
    const u16* zb = Zz + base;
    const u16* gb = Zg + base;
    u16* up = U4 + ((size_t)(br * NB + b * LL + c * CHL)) * DD + d0;
    int tbase = b * LL + c * CHL;
    for (int t0 = 0; t0 < CHL; t0 += 4) {
        int r[4];
        if (sip) {
            int4 il = *(const int4*)(sip + tbase + t0);
            r[0] = il.x; r[1] = il.y; r[2] = il.z; r[3] = il.w;
        } else {
            int l0 = c * CHL + t0;
            r[0] = l0; r[1] = l0 + 1; r[2] = l0 + 2; r[3] = l0 + 3;
        }
        u32 zv[4], gv[4];
#pragma unroll
        for (int e = 0; e < 4; ++e) {
            zv[e] = *(const u32*)(zb + (size_t)r[e] * DD);
            gv[e] = *(const u32*)(gb + (size_t)r[e] * DD);
        }
#pragma unroll
        for (int e = 0; e < 4; ++e) {
            float gA = b2f((u16)gv[e]), gB = b2f((u16)(gv[e] >> 16));
            hA = aA * hA + (1.f - aA) * b2f((u16)zv[e]);
            hB = aB * hB + (1.f - aB) * b2f((u16)(zv[e] >> 16));
            u32 o = (u32)f2b(hA * gA * sigm(gA)) | ((u32)f2b(hB * gB * sigm(gB)) << 16);
            *(u32*)(up + (size_t)(t0 + e) * DD) = o;
        }
    }
}

// --- batched agg, XCD swizzle + 2-deep gather pipeline ----------------------
__global__ void agg4_kernel(const u16* __restrict__ V5, const int* __restrict__ csr4,
                            const int* __restrict__ cnt, const float* __restrict__ deg,
                            const int* __restrict__ maskp, u16* __restrict__ Yin) {
    int cpx = gridDim.x >> 3;         // bijective (8192 % 8 == 0)
    int obid = blockIdx.x;
    int bid = (obid & 7) * cpx + (obid >> 3);
    int tr = threadIdx.x & 31;        // dims 8*tr..8*tr+7
    int rsub = threadIdx.x >> 5;      // 0..7
    int rg = bid * 8 + rsub;          // 0..NRT-1
    int br = rg >> 14, r = rg & (NB - 1), b = r >> 11;
    int n = cnt[r];
    const int* lst = csr4 + ((size_t)(br * NB + r)) * CAP;
    const u16* srcB = V5 + ((size_t)((br < 3 ? br : 4) * NB + (b << 11))) * DD + tr * 8;
    float acc[8] = {0.f, 0.f, 0.f, 0.f, 0.f, 0.f, 0.f, 0.f};
    int nb4 = n >> 2;
    union { uint4 q; u16 h[8]; } cur[4], nxt[4];
    if (nb4 > 0) {
        int4 il = *(const int4*)(lst);
        cur[0].q = *(const uint4*)(srcB + (size_t)il.x * DD);
        cur[1].q = *(const uint4*)(srcB + (size_t)il.y * DD);
        cur[2].q = *(const uint4*)(srcB + (size_t)il.z * DD);
        cur[3].q = *(const uint4*)(srcB + (size_t)il.w * DD);
    }
    for (int q = 0; q < nb4; ++q) {
        if (q + 1 < nb4) {
            int4 il = *(const int4*)(lst + (q + 1) * 4);
            nxt[0].q = *(const uint4*)(srcB + (size_t)il.x * DD);
            nxt[1].q = *(const uint4*)(srcB + (size_t)il.y * DD);
            nxt[2].q = *(const uint4*)(srcB + (size_t)il.z * DD);
            nxt[3].q = *(const uint4*)(srcB + (size_t)il.w * DD);
        }
#pragma unroll
        for (int k = 0; k < 8; ++k)
            acc[k] += b2f(cur[0].h[k]) + b2f(cur[1].h[k]) + b2f(cur[2].h[k]) + b2f(cur[3].h[k]);
#pragma unroll
        for (int e = 0; e < 4; ++e) cur[e] = nxt[e];
    }
    for (int i = nb4 * 4; i < n; ++i) {
        int idx = lst[i];
        union { uint4 q; u16 h[8]; } v;
        v.q = *(const uint4*)(srcB + (size_t)idx * DD);
#pragma unroll
        for (int k = 0; k < 8; ++k) acc[k] += b2f(v.h[k]);
    }
    float inv = 1.f / deg[r];
    int msk = maskp[r];
    union { uint4 q; u16 h[8]; } mo;
    if (br == 3) mo.q = *(const uint4*)(V5 + ((size_t)(3 * NB + r)) * DD + tr * 8);
    union { uint4 q; u16 h[8]; } o;
#pragma unroll
    for (int k = 0; k < 8; ++k) {
        float v = acc[k] * inv;
        v = v > 0.f ? v : 0.f;
        if (br == 3) v += b2f(mo.h[k]);
        v = msk ? v : 0.f;
        o.h[k] = f2b(v);
    }
    *(uint4*)(Yin + (size_t)r * 1024 + (br << 8) + tr * 8) = o.q;
}

// ---------------- layernorm, wave-per-row; Y = sum of two bf16 partials -----
__global__ void ln1_kernel(const u16* __restrict__ Ya, const u16* __restrict__ Yb,
                           const float* __restrict__ bvp,
                           const float* __restrict__ X, const float* __restrict__ gp,
                           const float* __restrict__ bp, u16* __restrict__ X1b) {
    int wv = threadIdx.x >> 6, lane = threadIdx.x & 63;
    int r = blockIdx.x * 4 + wv;
    int d0 = lane << 2;
    union { u64 q; u16 h[4]; } ya, yb;
    ya.q = *(const u64*)(Ya + (size_t)r * DD + d0);
    yb.q = *(const u64*)(Yb + (size_t)r * DD + d0);
    float4 bb = *(const float4*)(bvp + d0);
    float x[4];
#pragma unroll
    for (int k = 0; k < 4; ++k) x[k] = b2f(ya.h[k]) + b2f(yb.h[k]) + (&bb.x)[k];
    float s = x[0] + x[1] + x[2] + x[3];
#pragma unroll
    for (int o = 32; o > 0; o >>= 1) s += __shfl_xor(s, o, 64);
    float mu = s * (1.f / DD);
    float dx[4], ss = 0.f;
#pragma unroll
    for (int k = 0; k < 4; ++k) { dx[k] = x[k] - mu; ss += dx[k] * dx[k]; }
#pragma unroll
    for (int o = 32; o > 0; o >>= 1) ss += __shfl_xor(ss, o, 64);
    float rstd = rsqrtf(ss * (1.f / DD) + 1e-5f);
    float4 g4 = *(const float4*)(gp + d0);
    float4 b4 = *(const float4*)(bp + d0);
    float4 xv = *(const float4*)(X + (size_t)r * DD + d0);
    union { u64 q; u16 h[4]; } pk;
#pragma unroll
    for (int k = 0; k < 4; ++k) {
        float y = dx[k] * rstd * (&g4.x)[k] + (&b4.x)[k];
        pk.h[k] = f2b((&xv.x)[k] + y);
    }
    *(u64*)(X1b + (size_t)r * DD + d0) = pk.q;
}

__global__ void ln2_kernel(const u16* __restrict__ Ya, const u16* __restrict__ Yb,
                           const float* __restrict__ b2p,
                           const u16* __restrict__ X1b, const float* __restrict__ gp,
                           const float* __restrict__ bp, float* __restrict__ Out) {
    int wv = threadIdx.x >> 6, lane = threadIdx.x & 63;
    int r = blockIdx.x * 4 + wv;
    int d0 = lane << 2;
    union { u64 q; u16 h[4]; } ya, yb, x1;
    ya.q = *(const u64*)(Ya + (size_t)r * DD + d0);
    yb.q = *(const u64*)(Yb + (size_t)r * DD + d0);
    x1.q = *(const u64*)(X1b + (size_t)r * DD + d0);
    float4 bb = *(const float4*)(b2p + d0);
    float x[4];
#pragma unroll
    for (int k = 0; k < 4; ++k) x[k] = b2f(ya.h[k]) + b2f(yb.h[k]) + (&bb.x)[k];
    float s = x[0] + x[1] + x[2] + x[3];
#pragma unroll
    for (int o = 32; o > 0; o >>= 1) s += __shfl_xor(s, o, 64);
    float mu = s * (1.f / DD);
    float dx[4], ss = 0.f;
#pragma unroll
    for (int k = 0; k < 4; ++k) { dx[k] = x[k] - mu; ss += dx[k] * dx[k]; }
#pragma unroll
    for (int o = 32; o > 0; o >>= 1) ss += __shfl_xor(ss, o, 64);
    float rstd = rsqrtf(ss * (1.f / DD) + 1e-5f);
    float4 g4 = *(const float4*)(gp + d0);
    float4 b4 = *(const float4*)(bp + d0);
    float o4[4];
#pragma unroll
    for (int k = 0; k < 4; ++k)
        o4[k] = b2f(x1.h[k]) + dx[k] * rstd * (&g4.x)[k] + (&b4.x)[k];
    *(float4*)(Out + (size_t)r * DD + d0) = (float4){o4[0], o4[1], o4[2], o4[3]};
}

// ============================================================================
extern "C" void kernel_launch(void* const* d_in, const int* in_sizes, int n_in,
                              void* d_out, int out_size, void* d_ws, size_t ws_size,
                              hipStream_t stream) {
    const float* X      = (const float*)d_in[0];
    const int* maskp    = (const int*)d_in[1];
    const float* Adj    = (const float*)d_in[2];
    const int* si[3]    = { (const int*)d_in[3], (const int*)d_in[5], (const int*)d_in[7] };
    const int* ri[3]    = { (const int*)d_in[4], (const int*)d_in[6], (const int*)d_in[8] };
    const float* gm1_Win  = (const float*)d_in[9];
    const float* gm1_alog = (const float*)d_in[10];
    const float* gm1_Wout = (const float*)d_in[11];
    const float* gm2_We   = (const float*)d_in[12];
    const float* gm_Win   = (const float*)d_in[13];
    const float* gm_alog  = (const float*)d_in[14];
    const float* gm_Wout  = (const float*)d_in[15];
    const float* gm_We    = (const float*)d_in[16];
    const float* ln1_g    = (const float*)d_in[17];
    const float* ln1_b    = (const float*)d_in[18];
    const float* ln2_g    = (const float*)d_in[19];
    const float* ln2_b    = (const float*)d_in[20];
    const float* ffn_W1   = (const float*)d_in[21];
    const float* ffn_b1   = (const float*)d_in[22];
    const float* ffn_W2   = (const float*)d_in[23];
    const float* ffn_b2   = (const float*)d_in[24];
    const float* Wv       = (const float*)d_in[25];
    const float* bv       = (const float*)d_in[26];
    float* Out = (float*)d_out;

    char* ws = (char*)d_ws;
    size_t off = 0;
    auto alloc = [&](size_t bytes) { size_t o = off; off += (bytes + 255) & ~(size_t)255; return o; };

    u16* WinT1  = (u16*)(ws + alloc((size_t)512 * 256 * 2));
    u16* WinT   = (u16*)(ws + alloc((size_t)512 * 256 * 2));
    u16* WoutT  = (u16*)(ws + alloc((size_t)256 * 256 * 2));
    u16* WeT    = (u16*)(ws + alloc((size_t)256 * 256 * 2));
    u16* WvT    = (u16*)(ws + alloc((size_t)256 * 1024 * 2));
    u16* W1T    = (u16*)(ws + alloc((size_t)1024 * 256 * 2));
    u16* W2T    = (u16*)(ws + alloc((size_t)256 * 1024 * 2));
    u16* Wc1T   = (u16*)(ws + alloc((size_t)256 * 256 * 2));
    u16* Xb     = (u16*)(ws + alloc((size_t)NB * DD * 2));
    int* csr4 = (int*)(ws + alloc((size_t)4 * NB * CAP * 4));
    int* cnt = (int*)(ws + alloc((size_t)NB * 4));
    float* deg = (float*)(ws + alloc((size_t)NB * 4));
    float* carry = (float*)(ws + alloc((size_t)NBR * BB * NCH * DD * 4));
    u16* Zz  = (u16*)(ws + alloc((size_t)2 * NB * DD * 2));
    u16* Zg  = (u16*)(ws + alloc((size_t)2 * NB * DD * 2));
    u16* U4  = (u16*)(ws + alloc((size_t)4 * NB * DD * 2));
    u16* V5  = (u16*)(ws + alloc((size_t)5 * NB * DD * 2));
    u16* Yin = (u16*)(ws + alloc((size_t)NB * 1024 * 2));
    u16* tmpYa  = (u16*)(ws + alloc((size_t)NB * DD * 2));
    u16* tmpYb  = (u16*)(ws + alloc((size_t)NB * DD * 2));
    u16* X1b    = (u16*)(ws + alloc((size_t)NB * DD * 2));
    u16* H      = (u16*)(ws + alloc((size_t)NB * 1024 * 2));
    u16* tmpY2a = (u16*)(ws + alloc((size_t)NB * DD * 2));
    u16* tmpY2b = (u16*)(ws + alloc((size_t)NB * DD * 2));
    (void)ws_size; (void)in_sizes; (void)n_in; (void)out_size;

    // 1. prologue über-kernel: Wc1T | CSR | transposes | Xb
    PrologArgs ta;
    const float* srcs[7] = { gm1_Win, gm_Win, gm_Wout, gm_We, Wv, ffn_W1, ffn_W2 };
    u16* dsts[7]         = { WinT1,   WinT,   WoutT,   WeT,   WvT, W1T,   W2T };
    int Ks[7] = { 256, 256, 256, 256, 1024, 256, 1024 };
    int Ns[7] = { 512, 512, 256, 256, 256, 1024, 256 };
    int cum = 256 + NB;
    for (int i = 0; i < 7; ++i) {
        ta.s[i] = srcs[i]; ta.d[i] = dsts[i]; ta.K[i] = Ks[i]; ta.N[i] = Ns[i];
        ta.begT[i] = cum;
        cum += (Ks[i] * Ns[i]) / 256;
    }
    ta.begT[7] = cum;
    ta.xbBeg = cum; cum += NB * DD / 4 / 256;
    ta.xbEnd = cum;
    ta.xsrc = X; ta.maskp = maskp; ta.xdst = Xb;
    ta.Adj = Adj; ta.ri0 = ri[0]; ta.ri1 = ri[1]; ta.ri2 = ri[2];
    ta.csr4 = csr4; ta.cnt = cnt; ta.deg = deg;
    ta.wout1 = gm1_Wout; ta.we1 = gm2_We; ta.wc1t = Wc1T;
    prolog_kernel<<<cum, 256, 0, stream>>>(ta);

    // 2. Win GEMM (128x256 tiles): Z = [Xb@Win1 ; Xb@Win2] -> planar Zz/Zg
    gemm_win_kernel<<<dim3(2 * NB / 128, 2), 256, 0, stream>>>(
        Xb, WinT1, WinT, Zz, Zg);

    // 3-4. scan with fused si-gather (NCH=64) -> U4 (sorted order)
    scan_carry_kernel<<<NBR * BB * NCH, 128, 0, stream>>>(
        Zz, si[0], si[1], si[2], gm1_alog, gm_alog, carry);
    scan_apply_kernel<<<NBR * BB * NCH, 128, 0, stream>>>(
        Zz, Zg, si[0], si[1], si[2], gm1_alog, gm_alog, carry, U4);

    // 5. combined GEMM (128x256): rows [0,4NB) from U4, [4NB,5NB) from Xb -> V5
    gemm_kernel<<<dim3(5 * NB / 128, 1), 256, 0, stream>>>(
        U4, Xb, 4 * NB, Wc1T, WoutT, WeT, 3 * NB, 4 * NB,
        (void*)V5, nullptr, 256, 256, 2);

    // 6. fused aggregation (relu + mask + br3 mamba add), XCD swizzle -> Yin
    agg4_kernel<<<NRT / 8, 256, 0, stream>>>(V5, csr4, cnt, deg, maskp, Yin);

    // 7. Wv GEMM split-K2 (128x256): [NB,1024]@[1024,256] -> tmpYa+tmpYb
    gemm_splitk2_kernel<<<dim3(NB / 128, 1, 2), 256, 0, stream>>>(Yin, WvT, tmpYa, tmpYb);

    // 8. LN1 (+bv fold, +partial-sum add, +X residual) -> X1b bf16
    ln1_kernel<<<NB / 4, 256, 0, stream>>>(tmpYa, tmpYb, bv, X, ln1_g, ln1_b, X1b);

    // 9. FFN1 (128x256): [NB,256] @ [256,1024] +b1, relu -> H bf16
    gemm_kernel<<<dim3(NB / 128, 4), 256, 0, stream>>>(
        X1b, X1b, 1 << 30, W1T, W1T, W1T, 1 << 30, 1 << 30,
        (void*)H, ffn_b1, 1024, 256, 1);

    // 10. FFN2 split-K2 (128x256): [NB,1024]@[1024,256] -> tmpY2a+tmpY2b
    gemm_splitk2_kernel<<<dim3(NB / 128, 1, 2), 256, 0, stream>>>(H, W2T, tmpY2a, tmpY2b);

    // 11. LN2 (+b2 fold, +partial-sum add, +X1b residual) -> Out f32
    ln2_kernel<<<NB / 4, 256, 0, stream>>>(tmpY2a, tmpY2b, ffn_b2, X1b, ln2_g, ln2_b, Out);
}

// Round 16
// 225.431 us; speedup vs baseline: 1.1594x; 1.1594x over previous
//
#include <hip/hip_runtime.h>

typedef unsigned short u16;
typedef unsigned int u32;
typedef unsigned long long u64;

#define BB 8
#define LL 2048
#define DD 256
#define NB (BB * LL)      // 16384 rows per branch
#define NBR 4
#define NRT (NBR * NB)    // 65536 batched rows
#define NCH 64
#define CHL (LL / NCH)    // 32
#define CAP 64

typedef __attribute__((ext_vector_type(8))) __bf16 bf16x8;
typedef __attribute__((ext_vector_type(4))) float f32x4;

__device__ __forceinline__ float b2f(u16 u) {
    union { u32 u; float f; } x; x.u = ((u32)u) << 16; return x.f;
}
__device__ __forceinline__ u16 f2b(float f) {
    union { float f; u32 u; } x; x.f = f;
    u32 r = (x.u >> 16) & 1u;
    x.u += 0x7FFFu + r;
    return (u16)(x.u >> 16);
}
__device__ __forceinline__ float sigm(float x) { return 1.f / (1.f + __expf(-x)); }

#define GLD(gp, lp) __builtin_amdgcn_global_load_lds( \
    (const __attribute__((address_space(1))) void*)(gp), \
    (__attribute__((address_space(3))) void*)(lp), 16, 0, 0)

// ---- prologue über-kernel ---------------------------------------------------
// Block order: [0,256) Wc1T (1-blk/CU job first, overlaps CSR) | [256,256+NB) CSR
//            | transposes ×7 | Xb cast.
struct PrologArgs {
    const float* s[7];
    u16* d[7];
    int K[7], N[7];
    int begT[8];          // transpose job offsets
    int xbBeg, xbEnd;
    const float* xsrc;
    const int* maskp;
    u16* xdst;
    const float* Adj;
    const int* ri0; const int* ri1; const int* ri2;
    int* csr4; int* cnt; float* deg;
    const float* wout1; const float* we1;  // f32 originals
    u16* wc1t;
};
__global__ void prolog_kernel(PrologArgs a) {
    int blk = blockIdx.x;
    if (blk < 256) {                               // Wc1T[j][i] = sum_k Wout1[i][k]*We1[k][j]
        int ii = blk;
        int j = threadIdx.x;
        const float* wrow = a.wout1 + (size_t)ii * 256;
        const float* wcol = a.we1 + j;
        float a0 = 0.f, a1 = 0.f, a2 = 0.f, a3 = 0.f;
#pragma unroll 4
        for (int k = 0; k < 256; k += 4) {
            a0 += wrow[k]     * wcol[(size_t)k * 256];
            a1 += wrow[k + 1] * wcol[(size_t)(k + 1) * 256];
            a2 += wrow[k + 2] * wcol[(size_t)(k + 2) * 256];
            a3 += wrow[k + 3] * wcol[(size_t)(k + 3) * 256];
        }
        a.wc1t[(size_t)j * 256 + ii] = f2b((a0 + a1) + (a2 + a3));
        return;
    }
    if (blk < 256 + NB) {                          // CSR: 1 row/block, 4-wave compaction
        __shared__ int lidx[4][CAP];
        __shared__ int lcnt[4], pre[4], tot;
        int row = blk - 256;
        int w = threadIdx.x >> 6, lane = threadIdx.x & 63;
        int rowb = row & ~(LL - 1);                // (b<<11)
        const float* aseg = a.Adj + (size_t)row * LL + w * 512;
        float4 v0 = *(const float4*)(aseg + lane * 4);          // both loads in flight
        float4 v1 = *(const float4*)(aseg + 256 + lane * 4);    // before any ballot
        int base = 0;
#pragma unroll
        for (int it = 0; it < 2; ++it) {
            float4 v = it ? v1 : v0;
#pragma unroll
            for (int e = 0; e < 4; ++e) {
                float f = (e == 0) ? v.x : (e == 1) ? v.y : (e == 2) ? v.z : v.w;
                bool nz = (f != 0.f);
                u64 m = __ballot(nz);
                if (nz) {
                    int pos = base + __popcll(m & ((1ull << lane) - 1ull));
                    if (pos < CAP) lidx[w][pos] = w * 512 + it * 256 + lane * 4 + e;
                }
                base += __popcll(m);
            }
        }
        if (lane == 0) lcnt[w] = base;
        __syncthreads();
        if (threadIdx.x == 0) {
            int s = 0;
#pragma unroll
            for (int k = 0; k < 4; ++k) { pre[k] = s; s += lcnt[k]; }
            tot = s;
        }
        __syncthreads();
        int cw = lcnt[w]; if (cw > CAP) cw = CAP;
        int pw = pre[w];
        for (int k = lane; k < cw; k += 64) {
            int gpos = pw + k;
            if (gpos < CAP) {
                int j = lidx[w][k];
                a.csr4[((size_t)(3 * NB + row)) * CAP + gpos] = j;
                a.csr4[((size_t)(0 * NB + row)) * CAP + gpos] = a.ri0[rowb + j];
                a.csr4[((size_t)(1 * NB + row)) * CAP + gpos] = a.ri1[rowb + j];
                a.csr4[((size_t)(2 * NB + row)) * CAP + gpos] = a.ri2[rowb + j];
            }
        }
        if (threadIdx.x == 0) {
            int t = tot;
            a.cnt[row] = t < CAP ? t : CAP;
            a.deg[row] = (float)(t < 1 ? 1 : t);
        }
        return;
    }
    if (blk >= a.xbBeg) {                          // Xb = mask(X) -> bf16
        int g = (blk - a.xbBeg) * 256 + threadIdx.x;
        int r = g >> 6;                            // 64 quads per row
        float4 v = a.maskp[r] ? *(const float4*)(a.xsrc + (size_t)g * 4)
                              : (float4){0.f, 0.f, 0.f, 0.f};
        union { u64 q; u16 h[4]; } pk;
        pk.h[0] = f2b(v.x); pk.h[1] = f2b(v.y); pk.h[2] = f2b(v.z); pk.h[3] = f2b(v.w);
        *(u64*)(a.xdst + (size_t)g * 4) = pk.q;
        return;
    }
    int i = 0;                                     // weight transposes
    while (blk >= a.begT[i + 1]) ++i;
    int idx = (blk - a.begT[i]) * 256 + threadIdx.x;
    int K = a.K[i], N = a.N[i];
    if (idx >= K * N) return;
    int k = idx / N, n = idx - k * N;
    a.d[i][(size_t)n * K + k] = f2b(a.s[i][idx]);
}

// ------- Win GEMM: Z = [Xb@Win1 ; Xb@Win2], 2NB rows, planar z/g out --------
__global__ __launch_bounds__(256)
void gemm_win_kernel(const u16* __restrict__ Xb,
                     const u16* __restrict__ Bt1, const u16* __restrict__ Bt2,
                     u16* __restrict__ Zz, u16* __restrict__ Zg)
{
    __shared__ __align__(16) u16 As[2][128 * 32];
    __shared__ __align__(16) u16 Bs[2][128 * 32];
    int tid = threadIdx.x, lane = tid & 63;
    int w = tid >> 6, wm = w >> 1, wn = w & 1;
    int rowBase = blockIdx.x * 128, colBase = blockIdx.y * 128;
    const u16* Bt = (rowBase < NB) ? Bt1 : Bt2;
    int arow = rowBase & (NB - 1);

    const u16* pa[2];
    const u16* pb[2];
#pragma unroll
    for (int rep = 0; rep < 2; ++rep) {
        int s = rep * 256 + tid;
        int row = s >> 2, kk = (s & 3) << 3;
        pa[rep] = Xb + (size_t)(arow + row) * 256 + kk;
        pb[rep] = Bt + (size_t)(colBase + row) * 256 + kk;
    }

    f32x4 acc[4][4];
#pragma unroll
    for (int m = 0; m < 4; ++m)
#pragma unroll
        for (int n = 0; n < 4; ++n) acc[m][n] = (f32x4){0.f, 0.f, 0.f, 0.f};

#pragma unroll
    for (int rep = 0; rep < 2; ++rep) {
        int s = rep * 256 + tid;
        GLD(pa[rep], As[0] + s * 8);
        GLD(pb[rep], Bs[0] + s * 8);
    }
    int p = 0;
    for (int t = 0; t < 8; ++t) {
        if (t + 1 < 8) {
            int k0 = (t + 1) * 32;
#pragma unroll
            for (int rep = 0; rep < 2; ++rep) {
                int s = rep * 256 + tid;
                GLD(pa[rep] + k0, As[p ^ 1] + s * 8);
                GLD(pb[rep] + k0, Bs[p ^ 1] + s * 8);
            }
            asm volatile("s_waitcnt vmcnt(4)" ::: "memory");
        } else {
            asm volatile("s_waitcnt vmcnt(0)" ::: "memory");
        }
        __builtin_amdgcn_s_barrier();
        int kq = (lane >> 4) << 3;
        bf16x8 av[4], bw[4];
#pragma unroll
        for (int m = 0; m < 4; ++m)
            av[m] = *(const bf16x8*)(As[p] + (wm * 64 + m * 16 + (lane & 15)) * 32 + kq);
#pragma unroll
        for (int n = 0; n < 4; ++n)
            bw[n] = *(const bf16x8*)(Bs[p] + (wn * 64 + n * 16 + (lane & 15)) * 32 + kq);
#pragma unroll
        for (int m = 0; m < 4; ++m)
#pragma unroll
            for (int n = 0; n < 4; ++n)
                acc[m][n] = __builtin_amdgcn_mfma_f32_16x16x32_bf16(av[m], bw[n], acc[m][n], 0, 0, 0);
        __builtin_amdgcn_s_barrier();
        p ^= 1;
    }

    u16* Cz;
    int cb;
    if (colBase < 256) { Cz = Zz; cb = colBase; }
    else               { Cz = Zg; cb = colBase - 256; }
    int cBase = cb + wn * 64 + (lane & 15);
    int rBase = rowBase + wm * 64 + ((lane >> 4) << 2);
#pragma unroll
    for (int m = 0; m < 4; ++m)
#pragma unroll
        for (int n = 0; n < 4; ++n)
#pragma unroll
            for (int r = 0; r < 4; ++r)
                Cz[(size_t)(rBase + m * 16 + r) * 256 + (cBase + n * 16)] = f2b(acc[m][n][r]);
}

// --------- generic GEMM: 2-way A row-split, 3-way B weights, dbuf pipeline --
// mode 1: bias(f32)+relu+bf16; mode 2: plain bf16
__global__ __launch_bounds__(256)
void gemm_kernel(const u16* __restrict__ A1, const u16* __restrict__ A2, int asplit,
                 const u16* __restrict__ Bt1, const u16* __restrict__ Bt2,
                 const u16* __restrict__ Bt3, int split1, int split2,
                 void* __restrict__ Cout, const float* __restrict__ bias,
                 int N, int K, int mode)
{
    __shared__ __align__(16) u16 As[2][128 * 32];
    __shared__ __align__(16) u16 Bs[2][128 * 32];
    int tid = threadIdx.x;
    int lane = tid & 63;
    int w = tid >> 6, wm = w >> 1, wn = w & 1;
    int rowBase = blockIdx.x * 128, colBase = blockIdx.y * 128;
    const u16* Bt = (rowBase < split1) ? Bt1 : (rowBase < split2) ? Bt2 : Bt3;
    const u16* Arow = (rowBase < asplit) ? A1 + (size_t)rowBase * K
                                         : A2 + (size_t)(rowBase - asplit) * K;

    const u16* pa[2];
    const u16* pb[2];
#pragma unroll
    for (int rep = 0; rep < 2; ++rep) {
        int s = rep * 256 + tid;
        int row = s >> 2, kk = (s & 3) << 3;
        pa[rep] = Arow + (size_t)row * K + kk;
        pb[rep] = Bt + (size_t)(colBase + row) * K + kk;
    }

    f32x4 acc[4][4];
#pragma unroll
    for (int m = 0; m < 4; ++m)
#pragma unroll
        for (int n = 0; n < 4; ++n) acc[m][n] = (f32x4){0.f, 0.f, 0.f, 0.f};

    int nt = K >> 5;
#pragma unroll
    for (int rep = 0; rep < 2; ++rep) {
        int s = rep * 256 + tid;
        GLD(pa[rep], As[0] + s * 8);
        GLD(pb[rep], Bs[0] + s * 8);
    }
    int p = 0;
    for (int t = 0; t < nt; ++t) {
        if (t + 1 < nt) {
            int k0 = (t + 1) << 5;
#pragma unroll
            for (int rep = 0; rep < 2; ++rep) {
                int s = rep * 256 + tid;
                GLD(pa[rep] + k0, As[p ^ 1] + s * 8);
                GLD(pb[rep] + k0, Bs[p ^ 1] + s * 8);
            }
            asm volatile("s_waitcnt vmcnt(4)" ::: "memory");
        } else {
            asm volatile("s_waitcnt vmcnt(0)" ::: "memory");
        }
        __builtin_amdgcn_s_barrier();
        int kq = (lane >> 4) << 3;
        bf16x8 av[4], bw[4];
#pragma unroll
        for (int m = 0; m < 4; ++m)
            av[m] = *(const bf16x8*)(As[p] + (wm * 64 + m * 16 + (lane & 15)) * 32 + kq);
#pragma unroll
        for (int n = 0; n < 4; ++n)
            bw[n] = *(const bf16x8*)(Bs[p] + (wn * 64 + n * 16 + (lane & 15)) * 32 + kq);
#pragma unroll
        for (int m = 0; m < 4; ++m)
#pragma unroll
            for (int n = 0; n < 4; ++n)
                acc[m][n] = __builtin_amdgcn_mfma_f32_16x16x32_bf16(av[m], bw[n], acc[m][n], 0, 0, 0);
        __builtin_amdgcn_s_barrier();
        p ^= 1;
    }

    int cBase = colBase + wn * 64 + (lane & 15);
    int rBase = rowBase + wm * 64 + ((lane >> 4) << 2);
    u16* C = (u16*)Cout;
    float bz[4];
#pragma unroll
    for (int n = 0; n < 4; ++n) bz[n] = bias ? bias[cBase + n * 16] : 0.f;
#pragma unroll
    for (int m = 0; m < 4; ++m)
#pragma unroll
        for (int n = 0; n < 4; ++n)
#pragma unroll
            for (int r = 0; r < 4; ++r) {
                float v = acc[m][n][r] + bz[n];
                if (mode == 1) v = v > 0.f ? v : 0.f;
                C[(size_t)(rBase + m * 16 + r) * N + (cBase + n * 16)] = f2b(v);
            }
}

// --------- split-K2 GEMM for K=1024 (lda=ldb=1024): z picks K-half + output -
__global__ __launch_bounds__(256)
void gemm_splitk2_kernel(const u16* __restrict__ A, const u16* __restrict__ Bt,
                         u16* __restrict__ C0, u16* __restrict__ C1)
{
    __shared__ __align__(16) u16 As[2][128 * 32];
    __shared__ __align__(16) u16 Bs[2][128 * 32];
    int tid = threadIdx.x;
    int lane = tid & 63;
    int w = tid >> 6, wm = w >> 1, wn = w & 1;
    int rowBase = blockIdx.x * 128, colBase = blockIdx.y * 128;
    int koff = blockIdx.z * 512;

    const u16* pa[2];
    const u16* pb[2];
#pragma unroll
    for (int rep = 0; rep < 2; ++rep) {
        int s = rep * 256 + tid;
        int row = s >> 2, kk = (s & 3) << 3;
        pa[rep] = A + (size_t)(rowBase + row) * 1024 + koff + kk;
        pb[rep] = Bt + (size_t)(colBase + row) * 1024 + koff + kk;
    }

    f32x4 acc[4][4];
#pragma unroll
    for (int m = 0; m < 4; ++m)
#pragma unroll
        for (int n = 0; n < 4; ++n) acc[m][n] = (f32x4){0.f, 0.f, 0.f, 0.f};

#pragma unroll
    for (int rep = 0; rep < 2; ++rep) {
        int s = rep * 256 + tid;
        GLD(pa[rep], As[0] + s * 8);
        GLD(pb[rep], Bs[0] + s * 8);
    }
    int p = 0;
    for (int t = 0; t < 16; ++t) {
        if (t + 1 < 16) {
            int k0 = (t + 1) << 5;
#pragma unroll
            for (int rep = 0; rep < 2; ++rep) {
                int s = rep * 256 + tid;
                GLD(pa[rep] + k0, As[p ^ 1] + s * 8);
                GLD(pb[rep] + k0, Bs[p ^ 1] + s * 8);
            }
            asm volatile("s_waitcnt vmcnt(4)" ::: "memory");
        } else {
            asm volatile("s_waitcnt vmcnt(0)" ::: "memory");
        }
        __builtin_amdgcn_s_barrier();
        int kq = (lane >> 4) << 3;
        bf16x8 av[4], bw[4];
#pragma unroll
        for (int m = 0; m < 4; ++m)
            av[m] = *(const bf16x8*)(As[p] + (wm * 64 + m * 16 + (lane & 15)) * 32 + kq);
#pragma unroll
        for (int n = 0; n < 4; ++n)
            bw[n] = *(const bf16x8*)(Bs[p] + (wn * 64 + n * 16 + (lane & 15)) * 32 + kq);
#pragma unroll
        for (int m = 0; m < 4; ++m)
#pragma unroll
            for (int n = 0; n < 4; ++n)
                acc[m][n] = __builtin_amdgcn_mfma_f32_16x16x32_bf16(av[m], bw[n], acc[m][n], 0, 0, 0);
        __builtin_amdgcn_s_barrier();
        p ^= 1;
    }

    u16* C = blockIdx.z ? C1 : C0;
    int cBase = colBase + wn * 64 + (lane & 15);
    int rBase = rowBase + wm * 64 + ((lane >> 4) << 2);
#pragma unroll
    for (int m = 0; m < 4; ++m)
#pragma unroll
        for (int n = 0; n < 4; ++n)
#pragma unroll
            for (int r = 0; r < 4; ++r)
                C[(size_t)(rBase + m * 16 + r) * 256 + (cBase + n * 16)] = f2b(acc[m][n][r]);
}

// ------- scan with fused row-gather (si-permuted reads of shared Z) ---------
__global__ void scan_carry_kernel(const u16* __restrict__ Zz,
                                  const int* __restrict__ si0, const int* __restrict__ si1,
                                  const int* __restrict__ si2,
                                  const float* __restrict__ alog1, const float* __restrict__ alog2,
                                  float* __restrict__ carry) {
    int bid = blockIdx.x;                          // (br,b,c): 4*8*64 = 2048
    int br = bid >> 9, b = (bid >> 6) & 7, c = bid & 63;
    int d0 = threadIdx.x * 2;                      // 128 threads
    const float* al = (br < 3) ? alog1 : alog2;
    const int* sip = (br == 0) ? si0 : (br == 1) ? si1 : (br == 2) ? si2 : nullptr;
    float aA = sigm(al[d0]), aB = sigm(al[d0 + 1]);
    float hA = 0.f, hB = 0.f;
    const u16* zb = Zz + (((size_t)(br < 3 ? 0 : NB) + ((size_t)b << 11)) * DD) + d0;
    int tbase = b * LL + c * CHL;
    for (int t0 = 0; t0 < CHL; t0 += 4) {
        int r0, r1, r2, r3;
        if (sip) {
            int4 il = *(const int4*)(sip + tbase + t0);
            r0 = il.x; r1 = il.y; r2 = il.z; r3 = il.w;
        } else {
            int l0 = c * CHL + t0;
            r0 = l0; r1 = l0 + 1; r2 = l0 + 2; r3 = l0 + 3;
        }
        u32 v0 = *(const u32*)(zb + (size_t)r0 * DD);
        u32 v1 = *(const u32*)(zb + (size_t)r1 * DD);
        u32 v2 = *(const u32*)(zb + (size_t)r2 * DD);
        u32 v3 = *(const u32*)(zb + (size_t)r3 * DD);
        hA = aA * hA + (1.f - aA) * b2f((u16)v0); hB = aB * hB + (1.f - aB) * b2f((u16)(v0 >> 16));
        hA = aA * hA + (1.f - aA) * b2f((u16)v1); hB = aB * hB + (1.f - aB) * b2f((u16)(v1 >> 16));
        hA = aA * hA + (1.f - aA) * b2f((u16)v2); hB = aB * hB + (1.f - aB) * b2f((u16)(v2 >> 16));
        hA = aA * hA + (1.f - aA) * b2f((u16)v3); hB = aB * hB + (1.f - aB) * b2f((u16)(v3 >> 16));
    }
    carry[(size_t)bid * DD + d0] = hA;
    carry[(size_t)bid * DD + d0 + 1] = hB;
}

__global__ void scan_apply_kernel(const u16* __restrict__ Zz, const u16* __restrict__ Zg,
                                  const int* __restrict__ si0, const int* __restrict__ si1,
                                  const int* __restrict__ si2,
                                  const float* __restrict__ alog1, const float* __restrict__ alog2,
                                  const float* __restrict__ carry, u16* __restrict__ U4) {
    int bid = blockIdx.x;
    int br = bid >> 9, b = (bid >> 6) & 7, c = bid & 63;
    int d0 = threadIdx.x * 2;
    const float* al = (br < 3) ? alog1 : alog2;
    const int* sip = (br == 0) ? si0 : (br == 1) ? si1 : (br == 2) ? si2 : nullptr;
    float aA = sigm(al[d0]), aB = sigm(al[d0 + 1]);
    float aPA = aA, aPB = aB;
#pragma unroll
    for (int i = 0; i < 5; ++i) { aPA *= aPA; aPB *= aPB; }   // a^32
    float hA = 0.f, hB = 0.f;
    const float* cp = carry + ((size_t)((br * 8 + b) * NCH)) * DD + d0;
    for (int cc = 0; cc < c; ++cc) {
        float2 cv = *(const float2*)(cp + (size_t)cc * DD);
        hA = cv.x + aPA * hA;
        hB = cv.y + aPB * hB;
    }
    size_t base = ((size_t)(br < 3 ? 0 : NB) + ((size_t)b << 11)) * DD + d0;
    const u16* zb = Zz + base;
    const u16* gb = Zg + base;
    u16* up = U4 + ((size_t)(br * NB + b * LL + c * CHL)) * DD + d0;
    int tbase = b * LL + c * CHL;
    for (int t0 = 0; t0 < CHL; t0 += 4) {
        int r[4];
        if (sip) {
            int4 il = *(const int4*)(sip + tbase + t0);
            r[0] = il.x; r[1] = il.y; r[2] = il.z; r[3] = il.w;
        } else {
            int l0 = c * CHL + t0;
            r[0] = l0; r[1] = l0 + 1; r[2] = l0 + 2; r[3] = l0 + 3;
        }
        u32 zv[4], gv[4];
#pragma unroll
        for (int e = 0; e < 4; ++e) {
            zv[e] = *(const u32*)(zb + (size_t)r[e] * DD);
            gv[e] = *(const u32*)(gb + (size_t)r[e] * DD);
        }
#pragma unroll
        for (int e = 0; e < 4; ++e) {
            float gA = b2f((u16)gv[e]), gB = b2f((u16)(gv[e] >> 16));
            hA = aA * hA + (1.f - aA) * b2f((u16)zv[e]);
            hB = aB * hB + (1.f - aB) * b2f((u16)(zv[e] >> 16));
            u32 o = (u32)f2b(hA * gA * sigm(gA)) | ((u32)f2b(hB * gB * sigm(gB)) << 16);
            *(u32*)(up + (size_t)(t0 + e) * DD) = o;
        }
    }
}

// --- batched agg, XCD swizzle + 2-deep gather pipeline ----------------------
__global__ void agg4_kernel(const u16* __restrict__ V5, const int* __restrict__ csr4,
                            const int* __restrict__ cnt, const float* __restrict__ deg,
                            const int* __restrict__ maskp, u16* __restrict__ Yin) {
    int cpx = gridDim.x >> 3;         // bijective (8192 % 8 == 0)
    int obid = blockIdx.x;
    int bid = (obid & 7) * cpx + (obid >> 3);
    int tr = threadIdx.x & 31;        // dims 8*tr..8*tr+7
    int rsub = threadIdx.x >> 5;      // 0..7
    int rg = bid * 8 + rsub;          // 0..NRT-1
    int br = rg >> 14, r = rg & (NB - 1), b = r >> 11;
    int n = cnt[r];
    const int* lst = csr4 + ((size_t)(br * NB + r)) * CAP;
    const u16* srcB = V5 + ((size_t)((br < 3 ? br : 4) * NB + (b << 11))) * DD + tr * 8;
    float acc[8] = {0.f, 0.f, 0.f, 0.f, 0.f, 0.f, 0.f, 0.f};
    int nb4 = n >> 2;                 // full quads
    union { uint4 q; u16 h[8]; } cur[4], nxt[4];
    if (nb4 > 0) {
        int4 il = *(const int4*)(lst);
        cur[0].q = *(const uint4*)(srcB + (size_t)il.x * DD);
        cur[1].q = *(const uint4*)(srcB + (size_t)il.y * DD);
        cur[2].q = *(const uint4*)(srcB + (size_t)il.z * DD);
        cur[3].q = *(const uint4*)(srcB + (size_t)il.w * DD);
    }
    for (int q = 0; q < nb4; ++q) {
        if (q + 1 < nb4) {            // prefetch next quad while reducing current
            int4 il = *(const int4*)(lst + (q + 1) * 4);
            nxt[0].q = *(const uint4*)(srcB + (size_t)il.x * DD);
            nxt[1].q = *(const uint4*)(srcB + (size_t)il.y * DD);
            nxt[2].q = *(const uint4*)(srcB + (size_t)il.z * DD);
            nxt[3].q = *(const uint4*)(srcB + (size_t)il.w * DD);
        }
#pragma unroll
        for (int k = 0; k < 8; ++k)
            acc[k] += b2f(cur[0].h[k]) + b2f(cur[1].h[k]) + b2f(cur[2].h[k]) + b2f(cur[3].h[k]);
#pragma unroll
        for (int e = 0; e < 4; ++e) cur[e] = nxt[e];
    }
    for (int i = nb4 * 4; i < n; ++i) {
        int idx = lst[i];
        union { uint4 q; u16 h[8]; } v;
        v.q = *(const uint4*)(srcB + (size_t)idx * DD);
#pragma unroll
        for (int k = 0; k < 8; ++k) acc[k] += b2f(v.h[k]);
    }
    float inv = 1.f / deg[r];
    int msk = maskp[r];
    union { uint4 q; u16 h[8]; } mo;
    if (br == 3) mo.q = *(const uint4*)(V5 + ((size_t)(3 * NB + r)) * DD + tr * 8);
    union { uint4 q; u16 h[8]; } o;
#pragma unroll
    for (int k = 0; k < 8; ++k) {
        float v = acc[k] * inv;
        v = v > 0.f ? v : 0.f;
        if (br == 3) v += b2f(mo.h[k]);
        v = msk ? v : 0.f;
        o.h[k] = f2b(v);
    }
    *(uint4*)(Yin + (size_t)r * 1024 + (br << 8) + tr * 8) = o.q;
}

// ---------------- layernorm, wave-per-row; Y = sum of two bf16 partials -----
__global__ void ln1_kernel(const u16* __restrict__ Ya, const u16* __restrict__ Yb,
                           const float* __restrict__ bvp,
                           const float* __restrict__ X, const float* __restrict__ gp,
                           const float* __restrict__ bp, u16* __restrict__ X1b) {
    int wv = threadIdx.x >> 6, lane = threadIdx.x & 63;
    int r = blockIdx.x * 4 + wv;
    int d0 = lane << 2;
    union { u64 q; u16 h[4]; } ya, yb;
    ya.q = *(const u64*)(Ya + (size_t)r * DD + d0);
    yb.q = *(const u64*)(Yb + (size_t)r * DD + d0);
    float4 bb = *(const float4*)(bvp + d0);
    float x[4];
#pragma unroll
    for (int k = 0; k < 4; ++k) x[k] = b2f(ya.h[k]) + b2f(yb.h[k]) + (&bb.x)[k];
    float s = x[0] + x[1] + x[2] + x[3];
#pragma unroll
    for (int o = 32; o > 0; o >>= 1) s += __shfl_xor(s, o, 64);
    float mu = s * (1.f / DD);
    float dx[4], ss = 0.f;
#pragma unroll
    for (int k = 0; k < 4; ++k) { dx[k] = x[k] - mu; ss += dx[k] * dx[k]; }
#pragma unroll
    for (int o = 32; o > 0; o >>= 1) ss += __shfl_xor(ss, o, 64);
    float rstd = rsqrtf(ss * (1.f / DD) + 1e-5f);
    float4 g4 = *(const float4*)(gp + d0);
    float4 b4 = *(const float4*)(bp + d0);
    float4 xv = *(const float4*)(X + (size_t)r * DD + d0);
    union { u64 q; u16 h[4]; } pk;
#pragma unroll
    for (int k = 0; k < 4; ++k) {
        float y = dx[k] * rstd * (&g4.x)[k] + (&b4.x)[k];
        pk.h[k] = f2b((&xv.x)[k] + y);
    }
    *(u64*)(X1b + (size_t)r * DD + d0) = pk.q;
}

__global__ void ln2_kernel(const u16* __restrict__ Ya, const u16* __restrict__ Yb,
                           const float* __restrict__ b2p,
                           const u16* __restrict__ X1b, const float* __restrict__ gp,
                           const float* __restrict__ bp, float* __restrict__ Out) {
    int wv = threadIdx.x >> 6, lane = threadIdx.x & 63;
    int r = blockIdx.x * 4 + wv;
    int d0 = lane << 2;
    union { u64 q; u16 h[4]; } ya, yb, x1;
    ya.q = *(const u64*)(Ya + (size_t)r * DD + d0);
    yb.q = *(const u64*)(Yb + (size_t)r * DD + d0);
    x1.q = *(const u64*)(X1b + (size_t)r * DD + d0);
    float4 bb = *(const float4*)(b2p + d0);
    float x[4];
#pragma unroll
    for (int k = 0; k < 4; ++k) x[k] = b2f(ya.h[k]) + b2f(yb.h[k]) + (&bb.x)[k];
    float s = x[0] + x[1] + x[2] + x[3];
#pragma unroll
    for (int o = 32; o > 0; o >>= 1) s += __shfl_xor(s, o, 64);
    float mu = s * (1.f / DD);
    float dx[4], ss = 0.f;
#pragma unroll
    for (int k = 0; k < 4; ++k) { dx[k] = x[k] - mu; ss += dx[k] * dx[k]; }
#pragma unroll
    for (int o = 32; o > 0; o >>= 1) ss += __shfl_xor(ss, o, 64);
    float rstd = rsqrtf(ss * (1.f / DD) + 1e-5f);
    float4 g4 = *(const float4*)(gp + d0);
    float4 b4 = *(const float4*)(bp + d0);
    float o4[4];
#pragma unroll
    for (int k = 0; k < 4; ++k)
        o4[k] = b2f(x1.h[k]) + dx[k] * rstd * (&g4.x)[k] + (&b4.x)[k];
    *(float4*)(Out + (size_t)r * DD + d0) = (float4){o4[0], o4[1], o4[2], o4[3]};
}

// ============================================================================
extern "C" void kernel_launch(void* const* d_in, const int* in_sizes, int n_in,
                              void* d_out, int out_size, void* d_ws, size_t ws_size,
                              hipStream_t stream) {
    const float* X      = (const float*)d_in[0];
    const int* maskp    = (const int*)d_in[1];
    const float* Adj    = (const float*)d_in[2];
    const int* si[3]    = { (const int*)d_in[3], (const int*)d_in[5], (const int*)d_in[7] };
    const int* ri[3]    = { (const int*)d_in[4], (const int*)d_in[6], (const int*)d_in[8] };
    const float* gm1_Win  = (const float*)d_in[9];
    const float* gm1_alog = (const float*)d_in[10];
    const float* gm1_Wout = (const float*)d_in[11];
    const float* gm2_We   = (const float*)d_in[12];
    const float* gm_Win   = (const float*)d_in[13];
    const float* gm_alog  = (const float*)d_in[14];
    const float* gm_Wout  = (const float*)d_in[15];
    const float* gm_We    = (const float*)d_in[16];
    const float* ln1_g    = (const float*)d_in[17];
    const float* ln1_b    = (const float*)d_in[18];
    const float* ln2_g    = (const float*)d_in[19];
    const float* ln2_b    = (const float*)d_in[20];
    const float* ffn_W1   = (const float*)d_in[21];
    const float* ffn_b1   = (const float*)d_in[22];
    const float* ffn_W2   = (const float*)d_in[23];
    const float* ffn_b2   = (const float*)d_in[24];
    const float* Wv       = (const float*)d_in[25];
    const float* bv       = (const float*)d_in[26];
    float* Out = (float*)d_out;

    char* ws = (char*)d_ws;
    size_t off = 0;
    auto alloc = [&](size_t bytes) { size_t o = off; off += (bytes + 255) & ~(size_t)255; return o; };

    u16* WinT1  = (u16*)(ws + alloc((size_t)512 * 256 * 2));
    u16* WinT   = (u16*)(ws + alloc((size_t)512 * 256 * 2));
    u16* WoutT  = (u16*)(ws + alloc((size_t)256 * 256 * 2));
    u16* WeT    = (u16*)(ws + alloc((size_t)256 * 256 * 2));
    u16* WvT    = (u16*)(ws + alloc((size_t)256 * 1024 * 2));
    u16* W1T    = (u16*)(ws + alloc((size_t)1024 * 256 * 2));
    u16* W2T    = (u16*)(ws + alloc((size_t)256 * 1024 * 2));
    u16* Wc1T   = (u16*)(ws + alloc((size_t)256 * 256 * 2));   // (Wout1@We1)^T, f32-accurate
    u16* Xb     = (u16*)(ws + alloc((size_t)NB * DD * 2));     // masked X bf16
    int* csr4 = (int*)(ws + alloc((size_t)4 * NB * CAP * 4));  // 16.8 MB
    int* cnt = (int*)(ws + alloc((size_t)NB * 4));
    float* deg = (float*)(ws + alloc((size_t)NB * 4));
    float* carry = (float*)(ws + alloc((size_t)NBR * BB * NCH * DD * 4));
    u16* Zz  = (u16*)(ws + alloc((size_t)2 * NB * DD * 2));    // 16.8 MB
    u16* Zg  = (u16*)(ws + alloc((size_t)2 * NB * DD * 2));
    u16* U4  = (u16*)(ws + alloc((size_t)4 * NB * DD * 2));
    u16* V5  = (u16*)(ws + alloc((size_t)5 * NB * DD * 2));
    u16* Yin = (u16*)(ws + alloc((size_t)NB * 1024 * 2));
    u16* tmpYa  = (u16*)(ws + alloc((size_t)NB * DD * 2));
    u16* tmpYb  = (u16*)(ws + alloc((size_t)NB * DD * 2));
    u16* X1b    = (u16*)(ws + alloc((size_t)NB * DD * 2));
    u16* H      = (u16*)(ws + alloc((size_t)NB * 1024 * 2));
    u16* tmpY2a = (u16*)(ws + alloc((size_t)NB * DD * 2));
    u16* tmpY2b = (u16*)(ws + alloc((size_t)NB * DD * 2));
    (void)ws_size; (void)in_sizes; (void)n_in; (void)out_size;

    // 1. prologue über-kernel: Wc1T | CSR | transposes | Xb
    PrologArgs ta;
    const float* srcs[7] = { gm1_Win, gm_Win, gm_Wout, gm_We, Wv, ffn_W1, ffn_W2 };
    u16* dsts[7]         = { WinT1,   WinT,   WoutT,   WeT,   WvT, W1T,   W2T };
    int Ks[7] = { 256, 256, 256, 256, 1024, 256, 1024 };
    int Ns[7] = { 512, 512, 256, 256, 256, 1024, 256 };
    int cum = 256 + NB;                            // Wc1T [0,256) + CSR [256,256+NB)
    for (int i = 0; i < 7; ++i) {
        ta.s[i] = srcs[i]; ta.d[i] = dsts[i]; ta.K[i] = Ks[i]; ta.N[i] = Ns[i];
        ta.begT[i] = cum;
        cum += (Ks[i] * Ns[i]) / 256;
    }
    ta.begT[7] = cum;
    ta.xbBeg = cum; cum += NB * DD / 4 / 256;      // xb job: 4096 blocks
    ta.xbEnd = cum;
    ta.xsrc = X; ta.maskp = maskp; ta.xdst = Xb;
    ta.Adj = Adj; ta.ri0 = ri[0]; ta.ri1 = ri[1]; ta.ri2 = ri[2];
    ta.csr4 = csr4; ta.cnt = cnt; ta.deg = deg;
    ta.wout1 = gm1_Wout; ta.we1 = gm2_We; ta.wc1t = Wc1T;
    prolog_kernel<<<cum, 256, 0, stream>>>(ta);

    // 2. Win GEMM: Z = [Xb@Win1 ; Xb@Win2] -> planar Zz/Zg (2NB rows)
    gemm_win_kernel<<<dim3(2 * NB / 128, 512 / 128), 256, 0, stream>>>(
        Xb, WinT1, WinT, Zz, Zg);

    // 3-4. scan with fused si-gather (NCH=64) -> U4 (sorted order)
    scan_carry_kernel<<<NBR * BB * NCH, 128, 0, stream>>>(
        Zz, si[0], si[1], si[2], gm1_alog, gm_alog, carry);
    scan_apply_kernel<<<NBR * BB * NCH, 128, 0, stream>>>(
        Zz, Zg, si[0], si[1], si[2], gm1_alog, gm_alog, carry, U4);

    // 5. combined GEMM: rows [0,4NB) from U4, [4NB,5NB) from Xb -> V5
    gemm_kernel<<<dim3(5 * NB / 128, 2), 256, 0, stream>>>(
        U4, Xb, 4 * NB, Wc1T, WoutT, WeT, 3 * NB, 4 * NB,
        (void*)V5, nullptr, 256, 256, 2);

    // 6. fused aggregation (relu + mask + br3 mamba add), XCD swizzle -> Yin
    agg4_kernel<<<NRT / 8, 256, 0, stream>>>(V5, csr4, cnt, deg, maskp, Yin);

    // 7. Wv GEMM split-K2: [NB,1024]@[1024,256] -> tmpYa + tmpYb (bf16)
    gemm_splitk2_kernel<<<dim3(NB / 128, 2, 2), 256, 0, stream>>>(Yin, WvT, tmpYa, tmpYb);

    // 8. LN1 (+bv fold, +partial-sum add, +X residual) -> X1b bf16
    ln1_kernel<<<NB / 4, 256, 0, stream>>>(tmpYa, tmpYb, bv, X, ln1_g, ln1_b, X1b);

    // 9. FFN1: [NB,256] @ [256,1024] +b1, relu -> H bf16
    gemm_kernel<<<dim3(NB / 128, 8), 256, 0, stream>>>(
        X1b, X1b, 1 << 30, W1T, W1T, W1T, 1 << 30, 1 << 30,
        (void*)H, ffn_b1, 1024, 256, 1);

    // 10. FFN2 split-K2: [NB,1024]@[1024,256] -> tmpY2a + tmpY2b (bf16)
    gemm_splitk2_kernel<<<dim3(NB / 128, 2, 2), 256, 0, stream>>>(H, W2T, tmpY2a, tmpY2b);

    // 11. LN2 (+b2 fold, +partial-sum add, +X1b residual) -> Out f32
    ln2_kernel<<<NB / 4, 256, 0, stream>>>(tmpY2a, tmpY2b, ffn_b2, X1b, ln2_g, ln2_b, Out);
}